// Round 1
// baseline (1101.829 us; speedup 1.0000x reference)
//
#include <hip/hip_runtime.h>
#include <hip/hip_bf16.h>
#include <math.h>

#define DD 128
#define EPSBN 1e-5f

// ---------- small helpers ----------
__device__ __forceinline__ float4 f4_add(float4 a, float4 b) {
    return make_float4(a.x + b.x, a.y + b.y, a.z + b.z, a.w + b.w);
}
__device__ __forceinline__ float4 f4_fma(float a, float4 b, float4 c) {
    c.x = fmaf(a, b.x, c.x); c.y = fmaf(a, b.y, c.y);
    c.z = fmaf(a, b.z, c.z); c.w = fmaf(a, b.w, c.w);
    return c;
}
__device__ __forceinline__ float leakyf(float v, float s) { return v > 0.f ? v : s * v; }

// ---------- zero scratch (counts + stat accumulators) ----------
__global__ __launch_bounds__(256) void k_zero(int* __restrict__ counts, float* __restrict__ stats,
                                              int n, int nstats) {
    int idx = blockIdx.x * 256 + threadIdx.x;
    if (idx < n) counts[idx] = 0;
    else if (idx - n < nstats) stats[idx - n] = 0.f;
}

// ---------- XL = x@W_l + b_l ; XR = x@W_r + b_r ----------
__global__ __launch_bounds__(256) void k_gemm_xlxr(
    const float* __restrict__ x, const float* __restrict__ Wl, const float* __restrict__ bl,
    const float* __restrict__ Wr, const float* __restrict__ br,
    float* __restrict__ XL, float* __restrict__ XR, int n)
{
    __shared__ float As[8 * 128];
    int tid = threadIdx.x;
    int row0 = blockIdx.x * 8;
    int lr = tid >> 5;  // which of the 8 rows this float4 belongs to
    if (row0 + lr < n)
        ((float4*)As)[tid] = ((const float4*)(x + (size_t)row0 * DD))[tid];
    else
        ((float4*)As)[tid] = make_float4(0.f, 0.f, 0.f, 0.f);
    __syncthreads();
    int ty = tid >> 5, tx = tid & 31;
    int row = row0 + ty;
    if (row >= n) return;
    const float* B; const float* bias; float* Out; int coff;
    if (tx < 16) { B = Wl; bias = bl; Out = XL; coff = tx * 8; }
    else         { B = Wr; bias = br; Out = XR; coff = tx * 8 - 128; }
    float4 acc0 = make_float4(0.f, 0.f, 0.f, 0.f), acc1 = acc0;
    #pragma unroll 8
    for (int k = 0; k < 128; ++k) {
        float a = As[ty * 128 + k];
        const float4* brow = (const float4*)(B + (size_t)k * DD + coff);
        acc0 = f4_fma(a, brow[0], acc0);
        acc1 = f4_fma(a, brow[1], acc1);
    }
    const float4* bi = (const float4*)(bias + coff);
    acc0 = f4_add(acc0, bi[0]);
    acc1 = f4_add(acc1, bi[1]);
    float4* outp = (float4*)(Out + (size_t)row * DD + coff);
    outp[0] = acc0; outp[1] = acc1;
}

// ---------- wT[k][ci][co] = conv_w[co][ci][k] ----------
__global__ __launch_bounds__(256) void k_transpose_w(const float* __restrict__ conv_w,
                                                     float* __restrict__ wT) {
    int idx = blockIdx.x * 256 + threadIdx.x;  // 3*128*128 = 49152
    if (idx >= 3 * 128 * 128) return;
    int k = idx >> 14;          // / 16384
    int r = idx & 16383;
    int ci = r >> 7, co = r & 127;
    wT[idx] = conv_w[(size_t)co * 384 + ci * 3 + k];
}

// ---------- CSR build ----------
__global__ __launch_bounds__(256) void k_hist(const int* __restrict__ dst, int* __restrict__ counts, int e) {
    int idx = blockIdx.x * 256 + threadIdx.x;
    if (idx < e) atomicAdd(&counts[dst[idx]], 1);
}

__global__ __launch_bounds__(1024) void k_scan(const int* __restrict__ counts,
                                               int* __restrict__ offsets, int* __restrict__ cursor, int n) {
    __shared__ int ps[1024];
    int t = threadIdx.x;
    int chunk = (n + 1023) >> 10;
    int b = t * chunk, e = min(b + chunk, n);
    int s = 0;
    for (int i = b; i < e; ++i) s += counts[i];
    ps[t] = s;
    __syncthreads();
    for (int off = 1; off < 1024; off <<= 1) {
        int v = (t >= off) ? ps[t - off] : 0;
        __syncthreads();
        ps[t] += v;
        __syncthreads();
    }
    int run = ps[t] - s;
    for (int i = b; i < e; ++i) {
        offsets[i] = run; cursor[i] = run;
        run += counts[i];
    }
    if (t == 1023) offsets[n] = ps[1023];
}

__global__ __launch_bounds__(256) void k_scatter(const int* __restrict__ dst, int* __restrict__ cursor,
                                                 int* __restrict__ edge_ids, int e) {
    int idx = blockIdx.x * 256 + threadIdx.x;
    if (idx >= e) return;
    int d = dst[idx];
    int pos = atomicAdd(&cursor[d], 1);
    edge_ids[pos] = idx;
}

// ---------- GATv2 aggregation: one wave per node, online softmax ----------
__global__ __launch_bounds__(256) void k_agg(
    const float* __restrict__ XL, const float* __restrict__ XR,
    const float* __restrict__ x, const int* __restrict__ src,
    const int* __restrict__ edge_ids, const int* __restrict__ offsets,
    const float* __restrict__ edge_attr, const float* __restrict__ We,
    const float* __restrict__ att, const float* __restrict__ bias_gat,
    const float* __restrict__ weight1, float* __restrict__ Z, int n)
{
    int wave = (blockIdx.x << 2) + (threadIdx.x >> 6);
    int lane = threadIdx.x & 63;
    if (wave >= n) return;
    int i = wave;
    int c = lane * 2;

    // softmax(weight1)
    float w0 = weight1[0], w1v = weight1[1];
    float mw = fmaxf(w0, w1v);
    float e0 = __expf(w0 - mw), e1 = __expf(w1v - mw);
    float winv = 1.f / (e0 + e1);
    float w1x = e0 * winv, w1a = e1 * winv;

    // per-lane W_e columns (c, c+1): 32 regs
    float wex[16], wey[16];
    #pragma unroll
    for (int k = 0; k < 16; ++k) {
        float2 w = *(const float2*)(We + k * DD + c);
        wex[k] = w.x; wey[k] = w.y;
    }
    float2 att2 = *(const float2*)(att + c);
    float2 xr2  = *(const float2*)(XR + (size_t)i * DD + c);
    float2 xl0  = *(const float2*)(XL + (size_t)i * DD + c);

    // self loop (edge feature = 0)
    float mx = xl0.x + xr2.x, my = xl0.y + xr2.y;
    mx = leakyf(mx, 0.2f); my = leakyf(my, 0.2f);
    float pd = mx * att2.x + my * att2.y;
    #pragma unroll
    for (int off = 32; off > 0; off >>= 1) pd += __shfl_xor(pd, off, 64);
    float M = pd, L = 1.f;
    float Ox = xl0.x, Oy = xl0.y;

    int offs = offsets[i], offe = offsets[i + 1];
    for (int p = offs; p < offe; ++p) {
        int e = edge_ids[p];
        int j = src[e];
        float2 xl2 = *(const float2*)(XL + (size_t)j * DD + c);
        const float4* ea4 = (const float4*)(edge_attr) + (size_t)e * 4;
        float4 a0 = ea4[0], a1 = ea4[1], a2 = ea4[2], a3 = ea4[3];
        float ea[16] = {a0.x, a0.y, a0.z, a0.w, a1.x, a1.y, a1.z, a1.w,
                        a2.x, a2.y, a2.z, a2.w, a3.x, a3.y, a3.z, a3.w};
        float ex = 0.f, ey = 0.f;
        #pragma unroll
        for (int k = 0; k < 16; ++k) {
            ex = fmaf(ea[k], wex[k], ex);
            ey = fmaf(ea[k], wey[k], ey);
        }
        float mmx = xl2.x + xr2.x + ex, mmy = xl2.y + xr2.y + ey;
        mmx = leakyf(mmx, 0.2f); mmy = leakyf(mmy, 0.2f);
        float pdd = mmx * att2.x + mmy * att2.y;
        #pragma unroll
        for (int off = 32; off > 0; off >>= 1) pdd += __shfl_xor(pdd, off, 64);
        float newM = fmaxf(M, pdd);
        float s = __expf(M - newM);
        float w = __expf(pdd - newM);
        Ox = Ox * s + w * xl2.x;
        Oy = Oy * s + w * xl2.y;
        L = L * s + w;
        M = newM;
    }
    float rl = 1.f / L;
    float2 bg = *(const float2*)(bias_gat + c);
    float ax = fmaf(Ox, rl, bg.x), ay = fmaf(Oy, rl, bg.y);
    float2 xv = *(const float2*)(x + (size_t)i * DD + c);
    float2 zv;
    zv.x = w1x * xv.x + w1a * ax;
    zv.y = w1x * xv.y + w1a * ay;
    *(float2*)(Z + (size_t)i * DD + c) = zv;
}

// ---------- per-column sums / sums-of-squares ----------
__global__ __launch_bounds__(256) void k_bn_stats(const float* __restrict__ Zin,
                                                  float* __restrict__ sums, float* __restrict__ sumsq, int n) {
    __shared__ float4 Ls[8][32];
    __shared__ float4 Lq[8][32];
    int tid = threadIdx.x;
    int cg = tid & 31, ry = tid >> 5;
    float4 s = make_float4(0.f, 0.f, 0.f, 0.f), q = s;
    for (int r = blockIdx.x * 8 + ry; r < n; r += gridDim.x * 8) {
        float4 v = ((const float4*)(Zin + (size_t)r * DD))[cg];
        s = f4_add(s, v);
        q.x = fmaf(v.x, v.x, q.x); q.y = fmaf(v.y, v.y, q.y);
        q.z = fmaf(v.z, v.z, q.z); q.w = fmaf(v.w, v.w, q.w);
    }
    Ls[ry][cg] = s; Lq[ry][cg] = q;
    __syncthreads();
    if (tid < 32) {
        float4 ts = Ls[0][tid], tq = Lq[0][tid];
        #pragma unroll
        for (int j = 1; j < 8; ++j) { ts = f4_add(ts, Ls[j][tid]); tq = f4_add(tq, Lq[j][tid]); }
        atomicAdd(&sums[tid * 4 + 0], ts.x); atomicAdd(&sums[tid * 4 + 1], ts.y);
        atomicAdd(&sums[tid * 4 + 2], ts.z); atomicAdd(&sums[tid * 4 + 3], ts.w);
        atomicAdd(&sumsq[tid * 4 + 0], tq.x); atomicAdd(&sumsq[tid * 4 + 1], tq.y);
        atomicAdd(&sumsq[tid * 4 + 2], tq.z); atomicAdd(&sumsq[tid * 4 + 3], tq.w);
    }
}

__global__ __launch_bounds__(128) void k_bn_finish(const float* __restrict__ sums, const float* __restrict__ sumsq,
                                                   const float* __restrict__ gamma, const float* __restrict__ beta,
                                                   float* __restrict__ scale, float* __restrict__ shift, int n) {
    int t = threadIdx.x;
    if (t >= 128) return;
    float fn = (float)n;
    float mu = sums[t] / fn;
    float var = sumsq[t] / fn - mu * mu;
    float rstd = rsqrtf(var + EPSBN);
    float sc = gamma[t] * rstd;
    scale[t] = sc;
    shift[t] = fmaf(-mu, sc, beta[t]);
}

// ---------- conv1d(k=3) over BN1(z) + leaky(0.01) + weight2 mix ----------
__global__ __launch_bounds__(256) void k_conv(
    const float* __restrict__ Z, const float* __restrict__ scale1, const float* __restrict__ shift1,
    const float* __restrict__ wT, const float* __restrict__ conv_b,
    const float* __restrict__ weight2, float* __restrict__ Z2, int n)
{
    __shared__ float Zs[18 * 129];  // +1 pad: kills 4-way bank conflict on a-broadcasts
    int tid = threadIdx.x;
    int r0 = blockIdx.x * 16;
    for (int idx = tid; idx < 18 * 128; idx += 256) {
        int lrow = idx >> 7, cc = idx & 127;
        int g = r0 - 1 + lrow;
        float v = 0.f;
        if (g >= 0 && g < n)
            v = fmaf(Z[(size_t)g * DD + cc], scale1[cc], shift1[cc]);
        Zs[lrow * 129 + cc] = v;
    }
    __syncthreads();

    float w0 = weight2[0], w1v = weight2[1];
    float mw = fmaxf(w0, w1v);
    float e0 = __expf(w0 - mw), e1 = __expf(w1v - mw);
    float winv = 1.f / (e0 + e1);
    float w2x = e0 * winv, w2a = e1 * winv;

    int ty = tid >> 4, tx = tid & 15;
    int row = r0 + ty;
    if (row >= n) return;
    int co = tx * 8;
    float4 acc0 = make_float4(0.f, 0.f, 0.f, 0.f), acc1 = acc0;
    #pragma unroll 4
    for (int ci = 0; ci < 128; ++ci) {
        float a0 = Zs[ty * 129 + ci];
        float a1 = Zs[(ty + 1) * 129 + ci];
        float a2 = Zs[(ty + 2) * 129 + ci];
        const float4* q0 = (const float4*)(wT + (size_t)ci * DD + co);
        const float4* q1 = (const float4*)(wT + 16384 + (size_t)ci * DD + co);
        const float4* q2 = (const float4*)(wT + 32768 + (size_t)ci * DD + co);
        acc0 = f4_fma(a0, q0[0], acc0); acc1 = f4_fma(a0, q0[1], acc1);
        acc0 = f4_fma(a1, q1[0], acc0); acc1 = f4_fma(a1, q1[1], acc1);
        acc0 = f4_fma(a2, q2[0], acc0); acc1 = f4_fma(a2, q2[1], acc1);
    }
    const float4* cb = (const float4*)(conv_b + co);
    acc0 = f4_add(acc0, cb[0]);
    acc1 = f4_add(acc1, cb[1]);
    float z1v[8] = {acc0.x, acc0.y, acc0.z, acc0.w, acc1.x, acc1.y, acc1.z, acc1.w};
    float outv[8];
    #pragma unroll
    for (int t = 0; t < 8; ++t) {
        float z1 = leakyf(z1v[t], 0.01f);
        float zbn = Zs[(ty + 1) * 129 + co + t];
        outv[t] = w2x * zbn + w2a * z1;
    }
    float4* outp = (float4*)(Z2 + (size_t)row * DD + co);
    outp[0] = make_float4(outv[0], outv[1], outv[2], outv[3]);
    outp[1] = make_float4(outv[4], outv[5], outv[6], outv[7]);
}

// ---------- final BN2 apply ----------
__global__ __launch_bounds__(256) void k_final(const float* __restrict__ Z2,
                                               const float* __restrict__ scale2, const float* __restrict__ shift2,
                                               float* __restrict__ out, int total4) {
    int idx = blockIdx.x * 256 + threadIdx.x;
    if (idx >= total4) return;
    int c4 = idx & 31;
    float4 v = ((const float4*)Z2)[idx];
    float4 sc = ((const float4*)scale2)[c4];
    float4 sh = ((const float4*)shift2)[c4];
    float4 r;
    r.x = fmaf(v.x, sc.x, sh.x); r.y = fmaf(v.y, sc.y, sh.y);
    r.z = fmaf(v.z, sc.z, sh.z); r.w = fmaf(v.w, sc.w, sh.w);
    ((float4*)out)[idx] = r;
}

extern "C" void kernel_launch(void* const* d_in, const int* in_sizes, int n_in,
                              void* d_out, int out_size, void* d_ws, size_t ws_size,
                              hipStream_t stream)
{
    const float* x          = (const float*)d_in[0];
    const int*   edge_index = (const int*)d_in[1];
    const float* edge_attr  = (const float*)d_in[2];
    const float* W_l        = (const float*)d_in[3];
    const float* b_l        = (const float*)d_in[4];
    const float* W_r        = (const float*)d_in[5];
    const float* b_r        = (const float*)d_in[6];
    const float* W_e        = (const float*)d_in[7];
    const float* att        = (const float*)d_in[8];
    const float* bias_gat   = (const float*)d_in[9];
    const float* weight1    = (const float*)d_in[10];
    const float* bn1_gamma  = (const float*)d_in[11];
    const float* bn1_beta   = (const float*)d_in[12];
    const float* conv_w     = (const float*)d_in[13];
    const float* conv_b     = (const float*)d_in[14];
    const float* weight2    = (const float*)d_in[15];
    const float* bn2_gamma  = (const float*)d_in[16];
    const float* bn2_beta   = (const float*)d_in[17];

    int n = in_sizes[0] / DD;   // 50000
    int e = in_sizes[1] / 2;    // 800000

    // ws layout (fp32 unless noted); total ~81 MB
    float* XL = (float*)d_ws;                 // n*128
    float* XR = XL + (size_t)n * DD;          // n*128
    float* Z  = XR + (size_t)n * DD;          // n*128
    float* wT = Z + (size_t)n * DD;           // 3*128*128
    float* stats = wT + 49152;                // 1024 floats
    float* sums1 = stats,       *sumsq1 = stats + 128;
    float* sums2 = stats + 256, *sumsq2 = stats + 384;
    float* scale1 = stats + 512, *shift1 = stats + 640;
    float* scale2 = stats + 768, *shift2 = stats + 896;
    int* counts  = (int*)(stats + 1024);      // n
    int* offsets = counts + n;                // n+1
    int* cursor  = offsets + n + 1;           // n
    int* edge_ids = cursor + n;               // e
    float* Z2 = XL;                           // alias: XL dead after k_agg

    const int* src = edge_index;
    const int* dst = edge_index + e;

    k_zero<<<(n + 512 + 255) / 256, 256, 0, stream>>>(counts, stats, n, 512);
    k_gemm_xlxr<<<(n + 7) / 8, 256, 0, stream>>>(x, W_l, b_l, W_r, b_r, XL, XR, n);
    k_transpose_w<<<192, 256, 0, stream>>>(conv_w, wT);
    k_hist<<<(e + 255) / 256, 256, 0, stream>>>(dst, counts, e);
    k_scan<<<1, 1024, 0, stream>>>(counts, offsets, cursor, n);
    k_scatter<<<(e + 255) / 256, 256, 0, stream>>>(dst, cursor, edge_ids, e);
    k_agg<<<(n + 3) / 4, 256, 0, stream>>>(XL, XR, x, src, edge_ids, offsets,
                                           edge_attr, W_e, att, bias_gat, weight1, Z, n);
    k_bn_stats<<<64, 256, 0, stream>>>(Z, sums1, sumsq1, n);
    k_bn_finish<<<1, 128, 0, stream>>>(sums1, sumsq1, bn1_gamma, bn1_beta, scale1, shift1, n);
    k_conv<<<(n + 15) / 16, 256, 0, stream>>>(Z, scale1, shift1, wT, conv_b, weight2, Z2, n);
    k_bn_stats<<<64, 256, 0, stream>>>(Z2, sums2, sumsq2, n);
    k_bn_finish<<<1, 128, 0, stream>>>(sums2, sumsq2, bn2_gamma, bn2_beta, scale2, shift2, n);
    k_final<<<(n * 32 + 255) / 256, 256, 0, stream>>>(Z2, scale2, shift2, (float*)d_out, n * 32);
}

// Round 2
// 806.731 us; speedup vs baseline: 1.3658x; 1.3658x over previous
//
#include <hip/hip_runtime.h>
#include <hip/hip_bf16.h>
#include <math.h>

#define DD 128
#define EPSBN 1e-5f

// ---------- small helpers ----------
__device__ __forceinline__ float4 f4_add(float4 a, float4 b) {
    return make_float4(a.x + b.x, a.y + b.y, a.z + b.z, a.w + b.w);
}
__device__ __forceinline__ float4 f4_fma(float a, float4 b, float4 c) {
    c.x = fmaf(a, b.x, c.x); c.y = fmaf(a, b.y, c.y);
    c.z = fmaf(a, b.z, c.z); c.w = fmaf(a, b.w, c.w);
    return c;
}
__device__ __forceinline__ float leakyf(float v, float s) { return v > 0.f ? v : s * v; }

// ---------- zero scratch (counts + stat accumulators) ----------
__global__ __launch_bounds__(256) void k_zero(int* __restrict__ counts, float* __restrict__ stats,
                                              int n, int nstats) {
    int idx = blockIdx.x * 256 + threadIdx.x;
    if (idx < n) counts[idx] = 0;
    else if (idx - n < nstats) stats[idx - n] = 0.f;
}

// ---------- XL = x@W_l + b_l ; XR = x@W_r + b_r  (tiled: 64 rows x 256 cols/block) ----------
__global__ __launch_bounds__(256) void k_gemm_xlxr(
    const float* __restrict__ x, const float* __restrict__ Wl, const float* __restrict__ bl,
    const float* __restrict__ Wr, const float* __restrict__ br,
    float* __restrict__ XL, float* __restrict__ XR, int n)
{
    __shared__ float As[64 * 33];        // 64 rows x 32 k (pad 33)
    __shared__ float Bs[32 * 256];       // [k][0:128 Wl | 128:256 Wr]  32 KB
    int tid = threadIdx.x;
    int r0 = blockIdx.x * 64;
    int tx = tid & 31, ty = tid >> 5;

    float4 accL[8], accR[8];
    #pragma unroll
    for (int j = 0; j < 8; ++j) {
        accL[j] = make_float4(0.f, 0.f, 0.f, 0.f);
        accR[j] = make_float4(0.f, 0.f, 0.f, 0.f);
    }

    for (int k0 = 0; k0 < 128; k0 += 32) {
        // A tile: 64x32
        for (int idx = tid; idx < 64 * 32; idx += 256) {
            int lrow = idx >> 5, kk = idx & 31;
            int g = r0 + lrow;
            As[lrow * 33 + kk] = (g < n) ? x[(size_t)g * DD + k0 + kk] : 0.f;
        }
        // B tile: 32k x 256co (float4 loads)
        for (int idx = tid; idx < 2048; idx += 256) {
            int kk = idx >> 6, co4 = idx & 63;
            float4 v;
            if (co4 < 32) v = ((const float4*)Wl)[(size_t)(k0 + kk) * 32 + co4];
            else          v = ((const float4*)Wr)[(size_t)(k0 + kk) * 32 + (co4 - 32)];
            ((float4*)Bs)[kk * 64 + co4] = v;
        }
        __syncthreads();

        #pragma unroll 4
        for (int kk = 0; kk < 32; ++kk) {
            float a[8];
            #pragma unroll
            for (int j = 0; j < 8; ++j) a[j] = As[(ty * 8 + j) * 33 + kk];
            float4 bL = ((float4*)Bs)[kk * 64 + tx];
            float4 bR = ((float4*)Bs)[kk * 64 + 32 + tx];
            #pragma unroll
            for (int j = 0; j < 8; ++j) {
                accL[j] = f4_fma(a[j], bL, accL[j]);
                accR[j] = f4_fma(a[j], bR, accR[j]);
            }
        }
        __syncthreads();
    }

    float4 blv = ((const float4*)bl)[tx];
    float4 brv = ((const float4*)br)[tx];
    #pragma unroll
    for (int j = 0; j < 8; ++j) {
        int row = r0 + ty * 8 + j;
        if (row < n) {
            ((float4*)(XL + (size_t)row * DD))[tx] = f4_add(accL[j], blv);
            ((float4*)(XR + (size_t)row * DD))[tx] = f4_add(accR[j], brv);
        }
    }
}

// ---------- wT[k][ci][co] = conv_w[co][ci][k] ----------
__global__ __launch_bounds__(256) void k_transpose_w(const float* __restrict__ conv_w,
                                                     float* __restrict__ wT) {
    int idx = blockIdx.x * 256 + threadIdx.x;  // 3*128*128 = 49152
    if (idx >= 3 * 128 * 128) return;
    int k = idx >> 14;
    int r = idx & 16383;
    int ci = r >> 7, co = r & 127;
    wT[idx] = conv_w[(size_t)co * 384 + ci * 3 + k];
}

// ---------- CSR build ----------
__global__ __launch_bounds__(256) void k_hist(const int* __restrict__ dst, int* __restrict__ counts, int e) {
    int idx = blockIdx.x * 256 + threadIdx.x;
    if (idx < e) atomicAdd(&counts[dst[idx]], 1);
}

__global__ __launch_bounds__(1024) void k_scan(const int* __restrict__ counts,
                                               int* __restrict__ offsets, int* __restrict__ cursor, int n) {
    __shared__ int ps[1024];
    int t = threadIdx.x;
    int chunk = (n + 1023) >> 10;
    int b = t * chunk, e = min(b + chunk, n);
    int s = 0;
    for (int i = b; i < e; ++i) s += counts[i];
    ps[t] = s;
    __syncthreads();
    for (int off = 1; off < 1024; off <<= 1) {
        int v = (t >= off) ? ps[t - off] : 0;
        __syncthreads();
        ps[t] += v;
        __syncthreads();
    }
    int run = ps[t] - s;
    for (int i = b; i < e; ++i) {
        offsets[i] = run; cursor[i] = run;
        run += counts[i];
    }
    if (t == 1023) offsets[n] = ps[1023];
}

__global__ __launch_bounds__(256) void k_scatter(const int* __restrict__ dst, int* __restrict__ cursor,
                                                 int* __restrict__ edge_ids, int e) {
    int idx = blockIdx.x * 256 + threadIdx.x;
    if (idx >= e) return;
    int d = dst[idx];
    int pos = atomicAdd(&cursor[d], 1);
    edge_ids[pos] = idx;
}

// ---------- GATv2 aggregation: one wave per node, online softmax ----------
__global__ __launch_bounds__(256) void k_agg(
    const float* __restrict__ XL, const float* __restrict__ XR,
    const float* __restrict__ x, const int* __restrict__ src,
    const int* __restrict__ edge_ids, const int* __restrict__ offsets,
    const float* __restrict__ edge_attr, const float* __restrict__ We,
    const float* __restrict__ att, const float* __restrict__ bias_gat,
    const float* __restrict__ weight1, float* __restrict__ Z, int n)
{
    int wave = (blockIdx.x << 2) + (threadIdx.x >> 6);
    int lane = threadIdx.x & 63;
    if (wave >= n) return;
    int i = wave;
    int c = lane * 2;

    float w0 = weight1[0], w1v = weight1[1];
    float mw = fmaxf(w0, w1v);
    float e0 = __expf(w0 - mw), e1 = __expf(w1v - mw);
    float winv = 1.f / (e0 + e1);
    float w1x = e0 * winv, w1a = e1 * winv;

    float wex[16], wey[16];
    #pragma unroll
    for (int k = 0; k < 16; ++k) {
        float2 w = *(const float2*)(We + k * DD + c);
        wex[k] = w.x; wey[k] = w.y;
    }
    float2 att2 = *(const float2*)(att + c);
    float2 xr2  = *(const float2*)(XR + (size_t)i * DD + c);
    float2 xl0  = *(const float2*)(XL + (size_t)i * DD + c);

    float mx = xl0.x + xr2.x, my = xl0.y + xr2.y;
    mx = leakyf(mx, 0.2f); my = leakyf(my, 0.2f);
    float pd = mx * att2.x + my * att2.y;
    #pragma unroll
    for (int off = 32; off > 0; off >>= 1) pd += __shfl_xor(pd, off, 64);
    float M = pd, L = 1.f;
    float Ox = xl0.x, Oy = xl0.y;

    int offs = offsets[i], offe = offsets[i + 1];
    for (int p = offs; p < offe; ++p) {
        int e = edge_ids[p];
        int j = src[e];
        float2 xl2 = *(const float2*)(XL + (size_t)j * DD + c);
        const float4* ea4 = (const float4*)(edge_attr) + (size_t)e * 4;
        float4 a0 = ea4[0], a1 = ea4[1], a2 = ea4[2], a3 = ea4[3];
        float ea[16] = {a0.x, a0.y, a0.z, a0.w, a1.x, a1.y, a1.z, a1.w,
                        a2.x, a2.y, a2.z, a2.w, a3.x, a3.y, a3.z, a3.w};
        float ex = 0.f, ey = 0.f;
        #pragma unroll
        for (int k = 0; k < 16; ++k) {
            ex = fmaf(ea[k], wex[k], ex);
            ey = fmaf(ea[k], wey[k], ey);
        }
        float mmx = xl2.x + xr2.x + ex, mmy = xl2.y + xr2.y + ey;
        mmx = leakyf(mmx, 0.2f); mmy = leakyf(mmy, 0.2f);
        float pdd = mmx * att2.x + mmy * att2.y;
        #pragma unroll
        for (int off = 32; off > 0; off >>= 1) pdd += __shfl_xor(pdd, off, 64);
        float newM = fmaxf(M, pdd);
        float s = __expf(M - newM);
        float w = __expf(pdd - newM);
        Ox = Ox * s + w * xl2.x;
        Oy = Oy * s + w * xl2.y;
        L = L * s + w;
        M = newM;
    }
    float rl = 1.f / L;
    float2 bg = *(const float2*)(bias_gat + c);
    float ax = fmaf(Ox, rl, bg.x), ay = fmaf(Oy, rl, bg.y);
    float2 xv = *(const float2*)(x + (size_t)i * DD + c);
    float2 zv;
    zv.x = w1x * xv.x + w1a * ax;
    zv.y = w1x * xv.y + w1a * ay;
    *(float2*)(Z + (size_t)i * DD + c) = zv;
}

// ---------- per-column sums / sums-of-squares ----------
__global__ __launch_bounds__(256) void k_bn_stats(const float* __restrict__ Zin,
                                                  float* __restrict__ sums, float* __restrict__ sumsq, int n) {
    __shared__ float4 Ls[8][32];
    __shared__ float4 Lq[8][32];
    int tid = threadIdx.x;
    int cg = tid & 31, ry = tid >> 5;
    float4 s = make_float4(0.f, 0.f, 0.f, 0.f), q = s;
    for (int r = blockIdx.x * 8 + ry; r < n; r += gridDim.x * 8) {
        float4 v = ((const float4*)(Zin + (size_t)r * DD))[cg];
        s = f4_add(s, v);
        q.x = fmaf(v.x, v.x, q.x); q.y = fmaf(v.y, v.y, q.y);
        q.z = fmaf(v.z, v.z, q.z); q.w = fmaf(v.w, v.w, q.w);
    }
    Ls[ry][cg] = s; Lq[ry][cg] = q;
    __syncthreads();
    if (tid < 32) {
        float4 ts = Ls[0][tid], tq = Lq[0][tid];
        #pragma unroll
        for (int j = 1; j < 8; ++j) { ts = f4_add(ts, Ls[j][tid]); tq = f4_add(tq, Lq[j][tid]); }
        atomicAdd(&sums[tid * 4 + 0], ts.x); atomicAdd(&sums[tid * 4 + 1], ts.y);
        atomicAdd(&sums[tid * 4 + 2], ts.z); atomicAdd(&sums[tid * 4 + 3], ts.w);
        atomicAdd(&sumsq[tid * 4 + 0], tq.x); atomicAdd(&sumsq[tid * 4 + 1], tq.y);
        atomicAdd(&sumsq[tid * 4 + 2], tq.z); atomicAdd(&sumsq[tid * 4 + 3], tq.w);
    }
}

__global__ __launch_bounds__(128) void k_bn_finish(const float* __restrict__ sums, const float* __restrict__ sumsq,
                                                   const float* __restrict__ gamma, const float* __restrict__ beta,
                                                   float* __restrict__ scale, float* __restrict__ shift, int n) {
    int t = threadIdx.x;
    if (t >= 128) return;
    float fn = (float)n;
    float mu = sums[t] / fn;
    float var = sumsq[t] / fn - mu * mu;
    float rstd = rsqrtf(var + EPSBN);
    float sc = gamma[t] * rstd;
    scale[t] = sc;
    shift[t] = fmaf(-mu, sc, beta[t]);
}

// ---------- conv1d(k=3) tiled GEMM: 64 rows x 128 co per block ----------
__global__ __launch_bounds__(256) void k_conv(
    const float* __restrict__ Z, const float* __restrict__ scale1, const float* __restrict__ shift1,
    const float* __restrict__ wT, const float* __restrict__ conv_b,
    const float* __restrict__ weight2, float* __restrict__ Z2, int n)
{
    __shared__ float As[66 * 33];          // halo rows r0-1..r0+64, ci-chunk 32 (pad 33)
    __shared__ float Bs[3 * 32 * 128];     // [k][ci][co]  48 KB
    int tid = threadIdx.x;
    int r0 = blockIdx.x * 64;
    int tx = tid & 31, ty = tid >> 5;
    int rbase = ty * 8;

    float4 acc[8];
    #pragma unroll
    for (int j = 0; j < 8; ++j) acc[j] = make_float4(0.f, 0.f, 0.f, 0.f);

    for (int ci0 = 0; ci0 < 128; ci0 += 32) {
        // A tile with halo: 66 rows x 32 ci, BN1 applied, zero-pad out of range
        for (int idx = tid; idx < 66 * 32; idx += 256) {
            int lrow = idx >> 5, ci = idx & 31;
            int g = r0 - 1 + lrow;
            int cc = ci0 + ci;
            float v = 0.f;
            if (g >= 0 && g < n)
                v = fmaf(Z[(size_t)g * DD + cc], scale1[cc], shift1[cc]);
            As[lrow * 33 + ci] = v;
        }
        // B tile: 3k x 32ci x 128co
        for (int idx = tid; idx < 3072; idx += 256) {
            int k = idx >> 10;
            int r = idx & 1023;
            int ci = r >> 5, co4 = r & 31;
            ((float4*)Bs)[idx] = ((const float4*)wT)[(size_t)k * 4096 + (ci0 + ci) * 32 + co4];
        }
        __syncthreads();

        #pragma unroll 2
        for (int ci = 0; ci < 32; ++ci) {
            float a[10];
            #pragma unroll
            for (int j = 0; j < 10; ++j) a[j] = As[(rbase + j) * 33 + ci];
            float4 b0 = ((float4*)Bs)[(0 * 32 + ci) * 32 + tx];
            float4 b1 = ((float4*)Bs)[(1 * 32 + ci) * 32 + tx];
            float4 b2 = ((float4*)Bs)[(2 * 32 + ci) * 32 + tx];
            #pragma unroll
            for (int j = 0; j < 8; ++j) {
                acc[j] = f4_fma(a[j],     b0, acc[j]);
                acc[j] = f4_fma(a[j + 1], b1, acc[j]);
                acc[j] = f4_fma(a[j + 2], b2, acc[j]);
            }
        }
        __syncthreads();
    }

    // epilogue: z1 = leaky(conv + bias, 0.01); out = w2x*BN1(z) + w2a*z1
    float w0 = weight2[0], w1v = weight2[1];
    float mw = fmaxf(w0, w1v);
    float e0 = __expf(w0 - mw), e1 = __expf(w1v - mw);
    float winv = 1.f / (e0 + e1);
    float w2x = e0 * winv, w2a = e1 * winv;

    float4 cb = ((const float4*)conv_b)[tx];
    float4 sc1 = ((const float4*)scale1)[tx];
    float4 sh1 = ((const float4*)shift1)[tx];
    #pragma unroll
    for (int j = 0; j < 8; ++j) {
        int row = r0 + rbase + j;
        if (row >= n) break;
        float4 z1 = f4_add(acc[j], cb);
        z1.x = leakyf(z1.x, 0.01f); z1.y = leakyf(z1.y, 0.01f);
        z1.z = leakyf(z1.z, 0.01f); z1.w = leakyf(z1.w, 0.01f);
        float4 zv = ((const float4*)(Z + (size_t)row * DD))[tx];
        float4 zbn;
        zbn.x = fmaf(zv.x, sc1.x, sh1.x); zbn.y = fmaf(zv.y, sc1.y, sh1.y);
        zbn.z = fmaf(zv.z, sc1.z, sh1.z); zbn.w = fmaf(zv.w, sc1.w, sh1.w);
        float4 o;
        o.x = w2x * zbn.x + w2a * z1.x; o.y = w2x * zbn.y + w2a * z1.y;
        o.z = w2x * zbn.z + w2a * z1.z; o.w = w2x * zbn.w + w2a * z1.w;
        ((float4*)(Z2 + (size_t)row * DD))[tx] = o;
    }
}

// ---------- final BN2 apply ----------
__global__ __launch_bounds__(256) void k_final(const float* __restrict__ Z2,
                                               const float* __restrict__ scale2, const float* __restrict__ shift2,
                                               float* __restrict__ out, int total4) {
    int idx = blockIdx.x * 256 + threadIdx.x;
    if (idx >= total4) return;
    int c4 = idx & 31;
    float4 v = ((const float4*)Z2)[idx];
    float4 sc = ((const float4*)scale2)[c4];
    float4 sh = ((const float4*)shift2)[c4];
    float4 r;
    r.x = fmaf(v.x, sc.x, sh.x); r.y = fmaf(v.y, sc.y, sh.y);
    r.z = fmaf(v.z, sc.z, sh.z); r.w = fmaf(v.w, sc.w, sh.w);
    ((float4*)out)[idx] = r;
}

extern "C" void kernel_launch(void* const* d_in, const int* in_sizes, int n_in,
                              void* d_out, int out_size, void* d_ws, size_t ws_size,
                              hipStream_t stream)
{
    const float* x          = (const float*)d_in[0];
    const int*   edge_index = (const int*)d_in[1];
    const float* edge_attr  = (const float*)d_in[2];
    const float* W_l        = (const float*)d_in[3];
    const float* b_l        = (const float*)d_in[4];
    const float* W_r        = (const float*)d_in[5];
    const float* b_r        = (const float*)d_in[6];
    const float* W_e        = (const float*)d_in[7];
    const float* att        = (const float*)d_in[8];
    const float* bias_gat   = (const float*)d_in[9];
    const float* weight1    = (const float*)d_in[10];
    const float* bn1_gamma  = (const float*)d_in[11];
    const float* bn1_beta   = (const float*)d_in[12];
    const float* conv_w     = (const float*)d_in[13];
    const float* conv_b     = (const float*)d_in[14];
    const float* weight2    = (const float*)d_in[15];
    const float* bn2_gamma  = (const float*)d_in[16];
    const float* bn2_beta   = (const float*)d_in[17];

    int n = in_sizes[0] / DD;   // 50000
    int e = in_sizes[1] / 2;    // 800000

    float* XL = (float*)d_ws;                 // n*128
    float* XR = XL + (size_t)n * DD;          // n*128
    float* Z  = XR + (size_t)n * DD;          // n*128
    float* wT = Z + (size_t)n * DD;           // 3*128*128
    float* stats = wT + 49152;                // 1024 floats
    float* sums1 = stats,       *sumsq1 = stats + 128;
    float* sums2 = stats + 256, *sumsq2 = stats + 384;
    float* scale1 = stats + 512, *shift1 = stats + 640;
    float* scale2 = stats + 768, *shift2 = stats + 896;
    int* counts  = (int*)(stats + 1024);      // n
    int* offsets = counts + n;                // n+1
    int* cursor  = offsets + n + 1;           // n
    int* edge_ids = cursor + n;               // e
    float* Z2 = XL;                           // alias: XL dead after k_agg

    const int* src = edge_index;
    const int* dst = edge_index + e;

    k_zero<<<(n + 512 + 255) / 256, 256, 0, stream>>>(counts, stats, n, 512);
    k_gemm_xlxr<<<(n + 63) / 64, 256, 0, stream>>>(x, W_l, b_l, W_r, b_r, XL, XR, n);
    k_transpose_w<<<192, 256, 0, stream>>>(conv_w, wT);
    k_hist<<<(e + 255) / 256, 256, 0, stream>>>(dst, counts, e);
    k_scan<<<1, 1024, 0, stream>>>(counts, offsets, cursor, n);
    k_scatter<<<(e + 255) / 256, 256, 0, stream>>>(dst, cursor, edge_ids, e);
    k_agg<<<(n + 3) / 4, 256, 0, stream>>>(XL, XR, x, src, edge_ids, offsets,
                                           edge_attr, W_e, att, bias_gat, weight1, Z, n);
    k_bn_stats<<<64, 256, 0, stream>>>(Z, sums1, sumsq1, n);
    k_bn_finish<<<1, 128, 0, stream>>>(sums1, sumsq1, bn1_gamma, bn1_beta, scale1, shift1, n);
    k_conv<<<(n + 63) / 64, 256, 0, stream>>>(Z, scale1, shift1, wT, conv_b, weight2, Z2, n);
    k_bn_stats<<<64, 256, 0, stream>>>(Z2, sums2, sumsq2, n);
    k_bn_finish<<<1, 128, 0, stream>>>(sums2, sumsq2, bn2_gamma, bn2_beta, scale2, shift2, n);
    k_final<<<(n * 32 + 255) / 256, 256, 0, stream>>>(Z2, scale2, shift2, (float*)d_out, n * 32);
}

// Round 3
// 800.618 us; speedup vs baseline: 1.3762x; 1.0076x over previous
//
#include <hip/hip_runtime.h>
#include <hip/hip_bf16.h>
#include <math.h>

#define DD 128
#define EPSBN 1e-5f

// ---------- small helpers ----------
__device__ __forceinline__ float4 f4_add(float4 a, float4 b) {
    return make_float4(a.x + b.x, a.y + b.y, a.z + b.z, a.w + b.w);
}
__device__ __forceinline__ float4 f4_fma(float a, float4 b, float4 c) {
    c.x = fmaf(a, b.x, c.x); c.y = fmaf(a, b.y, c.y);
    c.z = fmaf(a, b.z, c.z); c.w = fmaf(a, b.w, c.w);
    return c;
}
__device__ __forceinline__ float leakyf(float v, float s) { return v > 0.f ? v : s * v; }

// per-edge W_e projection partial for this lane's 2 channels
__device__ __forceinline__ void eproj2(const float4* __restrict__ ea4,
                                       const float* __restrict__ wex, const float* __restrict__ wey,
                                       float& ex, float& ey) {
    float4 a0 = ea4[0], a1 = ea4[1], a2 = ea4[2], a3 = ea4[3];
    float ea[16] = {a0.x, a0.y, a0.z, a0.w, a1.x, a1.y, a1.z, a1.w,
                    a2.x, a2.y, a2.z, a2.w, a3.x, a3.y, a3.z, a3.w};
    float x = 0.f, y = 0.f;
    #pragma unroll
    for (int k = 0; k < 16; ++k) {
        x = fmaf(ea[k], wex[k], x);
        y = fmaf(ea[k], wey[k], y);
    }
    ex = x; ey = y;
}

// ---------- prep: transpose conv_w AND zero counts/stats (independent work, one launch) ----------
__global__ __launch_bounds__(256) void k_prep(const float* __restrict__ conv_w, float* __restrict__ wT,
                                              int* __restrict__ counts, float* __restrict__ stats,
                                              int n, int nstats) {
    int idx = blockIdx.x * 256 + threadIdx.x;
    if (idx < 3 * 128 * 128) {
        int k = idx >> 14;
        int r = idx & 16383;
        int ci = r >> 7, co = r & 127;
        wT[idx] = conv_w[(size_t)co * 384 + ci * 3 + k];
    }
    int z = idx - 3 * 128 * 128;
    if (z >= 0) {
        if (z < n) counts[z] = 0;
        else if (z - n < nstats) stats[z - n] = 0.f;
    }
}

// ---------- XL = x@W_l + b_l ; XR = x@W_r + b_r  (tiled: 64 rows x 256 cols/block) ----------
__global__ __launch_bounds__(256) void k_gemm_xlxr(
    const float* __restrict__ x, const float* __restrict__ Wl, const float* __restrict__ bl,
    const float* __restrict__ Wr, const float* __restrict__ br,
    float* __restrict__ XL, float* __restrict__ XR, int n)
{
    __shared__ float As[64 * 33];
    __shared__ float Bs[32 * 256];
    int tid = threadIdx.x;
    int r0 = blockIdx.x * 64;
    int tx = tid & 31, ty = tid >> 5;

    float4 accL[8], accR[8];
    #pragma unroll
    for (int j = 0; j < 8; ++j) {
        accL[j] = make_float4(0.f, 0.f, 0.f, 0.f);
        accR[j] = make_float4(0.f, 0.f, 0.f, 0.f);
    }

    for (int k0 = 0; k0 < 128; k0 += 32) {
        for (int idx = tid; idx < 64 * 32; idx += 256) {
            int lrow = idx >> 5, kk = idx & 31;
            int g = r0 + lrow;
            As[lrow * 33 + kk] = (g < n) ? x[(size_t)g * DD + k0 + kk] : 0.f;
        }
        for (int idx = tid; idx < 2048; idx += 256) {
            int kk = idx >> 6, co4 = idx & 63;
            float4 v;
            if (co4 < 32) v = ((const float4*)Wl)[(size_t)(k0 + kk) * 32 + co4];
            else          v = ((const float4*)Wr)[(size_t)(k0 + kk) * 32 + (co4 - 32)];
            ((float4*)Bs)[kk * 64 + co4] = v;
        }
        __syncthreads();

        #pragma unroll 4
        for (int kk = 0; kk < 32; ++kk) {
            float a[8];
            #pragma unroll
            for (int j = 0; j < 8; ++j) a[j] = As[(ty * 8 + j) * 33 + kk];
            float4 bL = ((float4*)Bs)[kk * 64 + tx];
            float4 bR = ((float4*)Bs)[kk * 64 + 32 + tx];
            #pragma unroll
            for (int j = 0; j < 8; ++j) {
                accL[j] = f4_fma(a[j], bL, accL[j]);
                accR[j] = f4_fma(a[j], bR, accR[j]);
            }
        }
        __syncthreads();
    }

    float4 blv = ((const float4*)bl)[tx];
    float4 brv = ((const float4*)br)[tx];
    #pragma unroll
    for (int j = 0; j < 8; ++j) {
        int row = r0 + ty * 8 + j;
        if (row < n) {
            ((float4*)(XL + (size_t)row * DD))[tx] = f4_add(accL[j], blv);
            ((float4*)(XR + (size_t)row * DD))[tx] = f4_add(accR[j], brv);
        }
    }
}

// ---------- CSR build ----------
__global__ __launch_bounds__(256) void k_hist(const int* __restrict__ dst, int* __restrict__ counts, int e) {
    int idx = blockIdx.x * 256 + threadIdx.x;
    if (idx < e) atomicAdd(&counts[dst[idx]], 1);
}

__global__ __launch_bounds__(1024) void k_scan(const int* __restrict__ counts,
                                               int* __restrict__ offsets, int* __restrict__ cursor, int n) {
    __shared__ int ps[1024];
    int t = threadIdx.x;
    const int chunk = 52;               // 1024*52 >= n, multiple of 4 for int4 loads
    int b = t * chunk, eend = min(b + chunk, n);
    int s = 0;
    if (b < n) {
        int i = b;
        for (; i + 4 <= eend; i += 4) {
            int4 v = *(const int4*)(counts + i);
            s += v.x + v.y + v.z + v.w;
        }
        for (; i < eend; ++i) s += counts[i];
    }
    ps[t] = s;
    __syncthreads();
    for (int off = 1; off < 1024; off <<= 1) {
        int v = (t >= off) ? ps[t - off] : 0;
        __syncthreads();
        ps[t] += v;
        __syncthreads();
    }
    int run = ps[t] - s;
    for (int i = b; i < eend; ++i) {
        offsets[i] = run; cursor[i] = run;
        run += counts[i];
    }
    if (t == 1023) offsets[n] = ps[1023];
}

__global__ __launch_bounds__(256) void k_scatter(const int* __restrict__ src, const int* __restrict__ dst,
                                                 int* __restrict__ cursor,
                                                 int* __restrict__ edge_ids, int* __restrict__ src_sorted, int e) {
    int idx = blockIdx.x * 256 + threadIdx.x;
    if (idx >= e) return;
    int d = dst[idx];
    int pos = atomicAdd(&cursor[d], 1);
    edge_ids[pos] = idx;
    src_sorted[pos] = src[idx];
}

// ---------- GATv2 aggregation: one wave per node, online softmax, 4-edge ILP batches ----------
__global__ __launch_bounds__(256) void k_agg(
    const float* __restrict__ XL, const float* __restrict__ XR,
    const float* __restrict__ x,
    const int* __restrict__ edge_ids, const int* __restrict__ src_sorted,
    const int* __restrict__ offsets,
    const float* __restrict__ edge_attr, const float* __restrict__ We,
    const float* __restrict__ att, const float* __restrict__ bias_gat,
    const float* __restrict__ weight1, float* __restrict__ Z, int n)
{
    int wave = (blockIdx.x << 2) + (threadIdx.x >> 6);
    int lane = threadIdx.x & 63;
    if (wave >= n) return;
    int i = wave;
    int c = lane * 2;

    float w0 = weight1[0], w1v = weight1[1];
    float mw = fmaxf(w0, w1v);
    float e0 = __expf(w0 - mw), e1 = __expf(w1v - mw);
    float winv = 1.f / (e0 + e1);
    float w1x = e0 * winv, w1a = e1 * winv;

    float wex[16], wey[16];
    #pragma unroll
    for (int k = 0; k < 16; ++k) {
        float2 w = *(const float2*)(We + k * DD + c);
        wex[k] = w.x; wey[k] = w.y;
    }
    float2 att2 = *(const float2*)(att + c);
    float2 xr2  = *(const float2*)(XR + (size_t)i * DD + c);
    float2 xl0  = *(const float2*)(XL + (size_t)i * DD + c);

    // self loop (edge feature = 0)
    float mx = xl0.x + xr2.x, my = xl0.y + xr2.y;
    mx = leakyf(mx, 0.2f); my = leakyf(my, 0.2f);
    float pd = mx * att2.x + my * att2.y;
    #pragma unroll
    for (int off = 32; off > 0; off >>= 1) pd += __shfl_xor(pd, off, 64);
    float M = pd, L = 1.f;
    float Ox = xl0.x, Oy = xl0.y;

    int p = offsets[i], offe = offsets[i + 1];

    // ---- batched by 4: independent loads + interleaved chains ----
    for (; p + 4 <= offe; p += 4) {
        int e0i = edge_ids[p],     e1i = edge_ids[p + 1];
        int e2i = edge_ids[p + 2], e3i = edge_ids[p + 3];
        int j0 = src_sorted[p],     j1 = src_sorted[p + 1];
        int j2 = src_sorted[p + 2], j3 = src_sorted[p + 3];
        float2 x0 = *(const float2*)(XL + (size_t)j0 * DD + c);
        float2 x1 = *(const float2*)(XL + (size_t)j1 * DD + c);
        float2 x2 = *(const float2*)(XL + (size_t)j2 * DD + c);
        float2 x3 = *(const float2*)(XL + (size_t)j3 * DD + c);

        float ex0, ey0, ex1, ey1, ex2, ey2, ex3, ey3;
        eproj2((const float4*)edge_attr + (size_t)e0i * 4, wex, wey, ex0, ey0);
        eproj2((const float4*)edge_attr + (size_t)e1i * 4, wex, wey, ex1, ey1);
        eproj2((const float4*)edge_attr + (size_t)e2i * 4, wex, wey, ex2, ey2);
        eproj2((const float4*)edge_attr + (size_t)e3i * 4, wex, wey, ex3, ey3);

        float l0, l1, l2, l3;
        {
            float ax = leakyf(x0.x + xr2.x + ex0, 0.2f), ay = leakyf(x0.y + xr2.y + ey0, 0.2f);
            l0 = ax * att2.x + ay * att2.y;
            ax = leakyf(x1.x + xr2.x + ex1, 0.2f); ay = leakyf(x1.y + xr2.y + ey1, 0.2f);
            l1 = ax * att2.x + ay * att2.y;
            ax = leakyf(x2.x + xr2.x + ex2, 0.2f); ay = leakyf(x2.y + xr2.y + ey2, 0.2f);
            l2 = ax * att2.x + ay * att2.y;
            ax = leakyf(x3.x + xr2.x + ex3, 0.2f); ay = leakyf(x3.y + xr2.y + ey3, 0.2f);
            l3 = ax * att2.x + ay * att2.y;
        }
        #pragma unroll
        for (int off = 32; off > 0; off >>= 1) {
            l0 += __shfl_xor(l0, off, 64);
            l1 += __shfl_xor(l1, off, 64);
            l2 += __shfl_xor(l2, off, 64);
            l3 += __shfl_xor(l3, off, 64);
        }
        float newM = fmaxf(fmaxf(fmaxf(l0, l1), fmaxf(l2, l3)), M);
        float s  = __expf(M - newM);
        float g0 = __expf(l0 - newM), g1 = __expf(l1 - newM);
        float g2 = __expf(l2 - newM), g3 = __expf(l3 - newM);
        Ox = Ox * s + g0 * x0.x + g1 * x1.x + g2 * x2.x + g3 * x3.x;
        Oy = Oy * s + g0 * x0.y + g1 * x1.y + g2 * x2.y + g3 * x3.y;
        L  = L * s + g0 + g1 + g2 + g3;
        M = newM;
    }

    // ---- remainder ----
    for (; p < offe; ++p) {
        int e = edge_ids[p];
        int j = src_sorted[p];
        float2 xl2 = *(const float2*)(XL + (size_t)j * DD + c);
        float ex, ey;
        eproj2((const float4*)edge_attr + (size_t)e * 4, wex, wey, ex, ey);
        float mmx = leakyf(xl2.x + xr2.x + ex, 0.2f);
        float mmy = leakyf(xl2.y + xr2.y + ey, 0.2f);
        float pdd = mmx * att2.x + mmy * att2.y;
        #pragma unroll
        for (int off = 32; off > 0; off >>= 1) pdd += __shfl_xor(pdd, off, 64);
        float newM = fmaxf(M, pdd);
        float s = __expf(M - newM);
        float w = __expf(pdd - newM);
        Ox = Ox * s + w * xl2.x;
        Oy = Oy * s + w * xl2.y;
        L = L * s + w;
        M = newM;
    }

    float rl = 1.f / L;
    float2 bg = *(const float2*)(bias_gat + c);
    float ax = fmaf(Ox, rl, bg.x), ay = fmaf(Oy, rl, bg.y);
    float2 xv = *(const float2*)(x + (size_t)i * DD + c);
    float2 zv;
    zv.x = w1x * xv.x + w1a * ax;
    zv.y = w1x * xv.y + w1a * ay;
    *(float2*)(Z + (size_t)i * DD + c) = zv;
}

// ---------- per-column sums / sums-of-squares ----------
__global__ __launch_bounds__(256) void k_bn_stats(const float* __restrict__ Zin,
                                                  float* __restrict__ sums, float* __restrict__ sumsq, int n) {
    __shared__ float4 Ls[8][32];
    __shared__ float4 Lq[8][32];
    int tid = threadIdx.x;
    int cg = tid & 31, ry = tid >> 5;
    float4 s = make_float4(0.f, 0.f, 0.f, 0.f), q = s;
    for (int r = blockIdx.x * 8 + ry; r < n; r += gridDim.x * 8) {
        float4 v = ((const float4*)(Zin + (size_t)r * DD))[cg];
        s = f4_add(s, v);
        q.x = fmaf(v.x, v.x, q.x); q.y = fmaf(v.y, v.y, q.y);
        q.z = fmaf(v.z, v.z, q.z); q.w = fmaf(v.w, v.w, q.w);
    }
    Ls[ry][cg] = s; Lq[ry][cg] = q;
    __syncthreads();
    if (tid < 32) {
        float4 ts = Ls[0][tid], tq = Lq[0][tid];
        #pragma unroll
        for (int j = 1; j < 8; ++j) { ts = f4_add(ts, Ls[j][tid]); tq = f4_add(tq, Lq[j][tid]); }
        atomicAdd(&sums[tid * 4 + 0], ts.x); atomicAdd(&sums[tid * 4 + 1], ts.y);
        atomicAdd(&sums[tid * 4 + 2], ts.z); atomicAdd(&sums[tid * 4 + 3], ts.w);
        atomicAdd(&sumsq[tid * 4 + 0], tq.x); atomicAdd(&sumsq[tid * 4 + 1], tq.y);
        atomicAdd(&sumsq[tid * 4 + 2], tq.z); atomicAdd(&sumsq[tid * 4 + 3], tq.w);
    }
}

__global__ __launch_bounds__(128) void k_bn_finish(const float* __restrict__ sums, const float* __restrict__ sumsq,
                                                   const float* __restrict__ gamma, const float* __restrict__ beta,
                                                   float* __restrict__ scale, float* __restrict__ shift, int n) {
    int t = threadIdx.x;
    if (t >= 128) return;
    float fn = (float)n;
    float mu = sums[t] / fn;
    float var = sumsq[t] / fn - mu * mu;
    float rstd = rsqrtf(var + EPSBN);
    float sc = gamma[t] * rstd;
    scale[t] = sc;
    shift[t] = fmaf(-mu, sc, beta[t]);
}

// ---------- conv1d(k=3) tiled GEMM: 64 rows x 128 co per block ----------
__global__ __launch_bounds__(256) void k_conv(
    const float* __restrict__ Z, const float* __restrict__ scale1, const float* __restrict__ shift1,
    const float* __restrict__ wT, const float* __restrict__ conv_b,
    const float* __restrict__ weight2, float* __restrict__ Z2, int n)
{
    __shared__ float As[66 * 33];
    __shared__ float Bs[3 * 32 * 128];
    int tid = threadIdx.x;
    int r0 = blockIdx.x * 64;
    int tx = tid & 31, ty = tid >> 5;
    int rbase = ty * 8;

    float4 acc[8];
    #pragma unroll
    for (int j = 0; j < 8; ++j) acc[j] = make_float4(0.f, 0.f, 0.f, 0.f);

    for (int ci0 = 0; ci0 < 128; ci0 += 32) {
        for (int idx = tid; idx < 66 * 32; idx += 256) {
            int lrow = idx >> 5, ci = idx & 31;
            int g = r0 - 1 + lrow;
            int cc = ci0 + ci;
            float v = 0.f;
            if (g >= 0 && g < n)
                v = fmaf(Z[(size_t)g * DD + cc], scale1[cc], shift1[cc]);
            As[lrow * 33 + ci] = v;
        }
        for (int idx = tid; idx < 3072; idx += 256) {
            int k = idx >> 10;
            int r = idx & 1023;
            int ci = r >> 5, co4 = r & 31;
            ((float4*)Bs)[idx] = ((const float4*)wT)[(size_t)k * 4096 + (ci0 + ci) * 32 + co4];
        }
        __syncthreads();

        #pragma unroll 2
        for (int ci = 0; ci < 32; ++ci) {
            float a[10];
            #pragma unroll
            for (int j = 0; j < 10; ++j) a[j] = As[(rbase + j) * 33 + ci];
            float4 b0 = ((float4*)Bs)[(0 * 32 + ci) * 32 + tx];
            float4 b1 = ((float4*)Bs)[(1 * 32 + ci) * 32 + tx];
            float4 b2 = ((float4*)Bs)[(2 * 32 + ci) * 32 + tx];
            #pragma unroll
            for (int j = 0; j < 8; ++j) {
                acc[j] = f4_fma(a[j],     b0, acc[j]);
                acc[j] = f4_fma(a[j + 1], b1, acc[j]);
                acc[j] = f4_fma(a[j + 2], b2, acc[j]);
            }
        }
        __syncthreads();
    }

    float w0 = weight2[0], w1v = weight2[1];
    float mw = fmaxf(w0, w1v);
    float e0 = __expf(w0 - mw), e1 = __expf(w1v - mw);
    float winv = 1.f / (e0 + e1);
    float w2x = e0 * winv, w2a = e1 * winv;

    float4 cb = ((const float4*)conv_b)[tx];
    float4 sc1 = ((const float4*)scale1)[tx];
    float4 sh1 = ((const float4*)shift1)[tx];
    #pragma unroll
    for (int j = 0; j < 8; ++j) {
        int row = r0 + rbase + j;
        if (row >= n) break;
        float4 z1 = f4_add(acc[j], cb);
        z1.x = leakyf(z1.x, 0.01f); z1.y = leakyf(z1.y, 0.01f);
        z1.z = leakyf(z1.z, 0.01f); z1.w = leakyf(z1.w, 0.01f);
        float4 zv = ((const float4*)(Z + (size_t)row * DD))[tx];
        float4 zbn;
        zbn.x = fmaf(zv.x, sc1.x, sh1.x); zbn.y = fmaf(zv.y, sc1.y, sh1.y);
        zbn.z = fmaf(zv.z, sc1.z, sh1.z); zbn.w = fmaf(zv.w, sc1.w, sh1.w);
        float4 o;
        o.x = w2x * zbn.x + w2a * z1.x; o.y = w2x * zbn.y + w2a * z1.y;
        o.z = w2x * zbn.z + w2a * z1.z; o.w = w2x * zbn.w + w2a * z1.w;
        ((float4*)(Z2 + (size_t)row * DD))[tx] = o;
    }
}

// ---------- final BN2 apply ----------
__global__ __launch_bounds__(256) void k_final(const float* __restrict__ Z2,
                                               const float* __restrict__ scale2, const float* __restrict__ shift2,
                                               float* __restrict__ out, int total4) {
    int idx = blockIdx.x * 256 + threadIdx.x;
    if (idx >= total4) return;
    int c4 = idx & 31;
    float4 v = ((const float4*)Z2)[idx];
    float4 sc = ((const float4*)scale2)[c4];
    float4 sh = ((const float4*)shift2)[c4];
    float4 r;
    r.x = fmaf(v.x, sc.x, sh.x); r.y = fmaf(v.y, sc.y, sh.y);
    r.z = fmaf(v.z, sc.z, sh.z); r.w = fmaf(v.w, sc.w, sh.w);
    ((float4*)out)[idx] = r;
}

extern "C" void kernel_launch(void* const* d_in, const int* in_sizes, int n_in,
                              void* d_out, int out_size, void* d_ws, size_t ws_size,
                              hipStream_t stream)
{
    const float* x          = (const float*)d_in[0];
    const int*   edge_index = (const int*)d_in[1];
    const float* edge_attr  = (const float*)d_in[2];
    const float* W_l        = (const float*)d_in[3];
    const float* b_l        = (const float*)d_in[4];
    const float* W_r        = (const float*)d_in[5];
    const float* b_r        = (const float*)d_in[6];
    const float* W_e        = (const float*)d_in[7];
    const float* att        = (const float*)d_in[8];
    const float* bias_gat   = (const float*)d_in[9];
    const float* weight1    = (const float*)d_in[10];
    const float* bn1_gamma  = (const float*)d_in[11];
    const float* bn1_beta   = (const float*)d_in[12];
    const float* conv_w     = (const float*)d_in[13];
    const float* conv_b     = (const float*)d_in[14];
    const float* weight2    = (const float*)d_in[15];
    const float* bn2_gamma  = (const float*)d_in[16];
    const float* bn2_beta   = (const float*)d_in[17];

    int n = in_sizes[0] / DD;   // 50000
    int e = in_sizes[1] / 2;    // 800000

    float* XL = (float*)d_ws;                 // n*128
    float* XR = XL + (size_t)n * DD;          // n*128
    float* Z  = XR + (size_t)n * DD;          // n*128
    float* wT = Z + (size_t)n * DD;           // 3*128*128
    float* stats = wT + 49152;                // 1024 floats
    float* sums1 = stats,       *sumsq1 = stats + 128;
    float* sums2 = stats + 256, *sumsq2 = stats + 384;
    float* scale1 = stats + 512, *shift1 = stats + 640;
    float* scale2 = stats + 768, *shift2 = stats + 896;
    int* counts  = (int*)(stats + 1024);      // n
    int* offsets = counts + n;                // n+1
    int* cursor  = offsets + n + 1;           // n
    int* edge_ids = cursor + n;               // e
    int* src_sorted = edge_ids + e;           // e
    float* Z2 = XL;                           // alias: XL dead after k_agg

    const int* src = edge_index;
    const int* dst = edge_index + e;

    k_prep<<<(3 * 128 * 128 + n + 512 + 255) / 256, 256, 0, stream>>>(conv_w, wT, counts, stats, n, 512);
    k_gemm_xlxr<<<(n + 63) / 64, 256, 0, stream>>>(x, W_l, b_l, W_r, b_r, XL, XR, n);
    k_hist<<<(e + 255) / 256, 256, 0, stream>>>(dst, counts, e);
    k_scan<<<1, 1024, 0, stream>>>(counts, offsets, cursor, n);
    k_scatter<<<(e + 255) / 256, 256, 0, stream>>>(src, dst, cursor, edge_ids, src_sorted, e);
    k_agg<<<(n + 3) / 4, 256, 0, stream>>>(XL, XR, x, edge_ids, src_sorted, offsets,
                                           edge_attr, W_e, att, bias_gat, weight1, Z, n);
    k_bn_stats<<<64, 256, 0, stream>>>(Z, sums1, sumsq1, n);
    k_bn_finish<<<1, 128, 0, stream>>>(sums1, sumsq1, bn1_gamma, bn1_beta, scale1, shift1, n);
    k_conv<<<(n + 63) / 64, 256, 0, stream>>>(Z, scale1, shift1, wT, conv_b, weight2, Z2, n);
    k_bn_stats<<<64, 256, 0, stream>>>(Z2, sums2, sumsq2, n);
    k_bn_finish<<<1, 128, 0, stream>>>(sums2, sumsq2, bn2_gamma, bn2_beta, scale2, shift2, n);
    k_final<<<(n * 32 + 255) / 256, 256, 0, stream>>>(Z2, scale2, shift2, (float*)d_out, n * 32);
}